// Round 6
// baseline (743.929 us; speedup 1.0000x reference)
//
#include <hip/hip_runtime.h>
#include <hip/hip_bf16.h>

typedef __bf16 bf16_t;
typedef bf16_t bf16x4 __attribute__((ext_vector_type(4)));
typedef bf16_t bf16x8 __attribute__((ext_vector_type(8)));
typedef float f32x4 __attribute__((ext_vector_type(4)));
typedef unsigned int u32;

#define MFMA16(a, b, c) __builtin_amdgcn_mfma_f32_16x16x32_bf16((a), (b), (c), 0, 0, 0)

// element-index XOR swizzles (bf16 elems): XOR bits 3..5 keyed by row&7
__device__ __forceinline__ int sxi(int row, int e) { return row * 256 + (e ^ ((row & 7) << 3)); }
__device__ __forceinline__ int ski(int row, int e) { return row * 64 + (e ^ ((row & 7) << 3)); }

__device__ __forceinline__ u32 pk2(float a, float b) {
  union { bf16_t h[2]; u32 u; } x;
  x.h[0] = (bf16_t)a; x.h[1] = (bf16_t)b;
  return x.u;
}

// ---------------------------------------------------------------------------
// prep kernels
// ---------------------------------------------------------------------------
__global__ void transpose_to_bf16(const float* __restrict__ in, bf16_t* __restrict__ outp,
                                  int K, int N) {
  __shared__ float tile[32][33];
  const int k0 = blockIdx.x * 32;
  const int n0 = blockIdx.y * 32;
  const int tx = threadIdx.x;
  const int ty = threadIdx.y;
#pragma unroll
  for (int i = 0; i < 32; i += 8)
    tile[ty + i][tx] = in[(size_t)(k0 + ty + i) * N + (n0 + tx)];
  __syncthreads();
#pragma unroll
  for (int i = 0; i < 32; i += 8)
    outp[(size_t)(n0 + ty + i) * K + (k0 + tx)] = (bf16_t)tile[tx][ty + i];
}

__global__ void rope_table(const float* __restrict__ invf, float2* __restrict__ cs) {
  const int idx = blockIdx.x * 256 + threadIdx.x;  // 0..2047 = 64*32
  const int t = idx >> 5;
  const int i = idx & 31;
  const float f = (float)t * invf[i];
  cs[idx] = make_float2(cosf(f), sinf(f));
}

// ---------------------------------------------------------------------------
// fused temporal-axial attention, 32KB LDS; x read from HBM exactly once
// grid: 2048 = (b, hh*32+ww); block: 256 threads (4 waves, wave w = head w)
// ---------------------------------------------------------------------------
__global__ __launch_bounds__(256, 3) void taa_fused(
    const float* __restrict__ x, const bf16_t* __restrict__ wqkvT,
    const bf16_t* __restrict__ woutT, const float* __restrict__ bout,
    const float2* __restrict__ ropecs, float* __restrict__ out) {
  // x-tile[64][256] bf16 swizzled; after B2: 4 per-wave 8KB slices (K then P)
  __shared__ __attribute__((aligned(16))) bf16_t sX[64 * 256];  // 32 KB

  const int tid = threadIdx.x;
  const int w = tid >> 6;   // wave == head
  const int l = tid & 63;
  const int l16 = l & 15;
  const int g = l >> 4;  // 0..3

  const int site = blockIdx.x;
  const int b = site >> 10;
  const int sp = site & 1023;

  const size_t TS = 1024 * 256;  // time stride in elements
  const float* xp = x + (size_t)((b * 64) * 1024 + sp) * 256;
  float* op = out + (size_t)((b * 64) * 1024 + sp) * 256;

  // ---- P1: x tile (64x256 f32) -> sX bf16 (swizzled) ----
#pragma unroll
  for (int it = 0; it < 16; ++it) {
    const int idx = tid + it * 256;
    const int t = idx >> 6;
    const int c = (idx & 63) * 4;
    const float4 v = *(const float4*)(xp + (size_t)t * TS + c);
    bf16x4 o4;
    o4[0] = (bf16_t)v.x; o4[1] = (bf16_t)v.y; o4[2] = (bf16_t)v.z; o4[3] = (bf16_t)v.w;
    *(bf16x4*)&sX[sxi(t, c)] = o4;
  }
  __syncthreads();  // B1

  // ---- P2a: Q^T = WqT @ x^T  (C rows dd, cols t), rope, pack -> qtb ----
  u32 qtb[4][4][2];
  {
    f32x4 qt[4][4] = {};
#pragma unroll
    for (int k0 = 0; k0 < 256; k0 += 32) {
      const int ko = k0 + 8 * g;
      bf16x8 aw[4], bx[4];
#pragma unroll
      for (int m = 0; m < 4; ++m)
        aw[m] = *(const bf16x8*)&wqkvT[(size_t)(w * 64 + 16 * m + l16) * 256 + ko];
#pragma unroll
      for (int n = 0; n < 4; ++n) bx[n] = *(const bf16x8*)&sX[sxi(16 * n + l16, ko)];
#pragma unroll
      for (int m = 0; m < 4; ++m)
#pragma unroll
        for (int n = 0; n < 4; ++n) qt[m][n] = MFMA16(aw[m], bx[n], qt[m][n]);
    }
    // rope on Q^T: partner dd^1 lives in adjacent r of the same reg quad
    const float qs = 0.125f * 1.44269504088896f;
#pragma unroll
    for (int m = 0; m < 4; ++m)
#pragma unroll
      for (int n = 0; n < 4; ++n)
#pragma unroll
        for (int c = 0; c < 2; ++c) {
          const float v0 = qt[m][n][2 * c], v1 = qt[m][n][2 * c + 1];
          const float2 cs = ropecs[(16 * n + l16) * 32 + 8 * m + 2 * g + c];
          qtb[m][n][c] = pk2((v0 * cs.x - v1 * cs.y) * qs, (v1 * cs.x + v0 * cs.y) * qs);
        }
  }

  // ---- P2b: V = x @ Wv (from LDS x-tile), pack -> vb ----
  u32 vb[4][4][2];
  {
    f32x4 va[4][4] = {};
#pragma unroll
    for (int k0 = 0; k0 < 256; k0 += 32) {
      const int ko = k0 + 8 * g;
      bf16x8 ax[4], bw[4];
#pragma unroll
      for (int m = 0; m < 4; ++m) ax[m] = *(const bf16x8*)&sX[sxi(16 * m + l16, ko)];
#pragma unroll
      for (int n = 0; n < 4; ++n)
        bw[n] = *(const bf16x8*)&wqkvT[(size_t)(512 + w * 64 + 16 * n + l16) * 256 + ko];
#pragma unroll
      for (int m = 0; m < 4; ++m)
#pragma unroll
        for (int n = 0; n < 4; ++n) va[m][n] = MFMA16(ax[m], bw[n], va[m][n]);
    }
#pragma unroll
    for (int m = 0; m < 4; ++m)
#pragma unroll
      for (int n = 0; n < 4; ++n)
#pragma unroll
        for (int c = 0; c < 2; ++c) vb[m][n][c] = pk2(va[m][n][2 * c], va[m][n][2 * c + 1]);
  }

  // ---- P2c: K = x @ Wk (C rows s, cols dd), rope in place (kept f32 until B2) ----
  f32x4 ka[4][4] = {};
  {
#pragma unroll
    for (int k0 = 0; k0 < 256; k0 += 32) {
      const int ko = k0 + 8 * g;
      bf16x8 ax[4], bw[4];
#pragma unroll
      for (int m = 0; m < 4; ++m) ax[m] = *(const bf16x8*)&sX[sxi(16 * m + l16, ko)];
#pragma unroll
      for (int n = 0; n < 4; ++n)
        bw[n] = *(const bf16x8*)&wqkvT[(size_t)(256 + w * 64 + 16 * n + l16) * 256 + ko];
#pragma unroll
      for (int m = 0; m < 4; ++m)
#pragma unroll
        for (int n = 0; n < 4; ++n) ka[m][n] = MFMA16(ax[m], bw[n], ka[m][n]);
    }
    // rope K in place (partner lane l16^1)
#pragma unroll
    for (int m = 0; m < 4; ++m)
#pragma unroll
      for (int n = 0; n < 4; ++n)
#pragma unroll
        for (int r = 0; r < 4; ++r) {
          const float v = ka[m][n][r];
          const float p = __shfl_xor(v, 1);
          const int s = 16 * m + 4 * g + r;
          const int dd = 16 * n + l16;
          const float2 cs = ropecs[s * 32 + 8 * n + (l16 >> 1)];
          ka[m][n][r] = (dd & 1) ? (v * cs.x + p * cs.y) : (v * cs.x - p * cs.y);
        }
  }
  __syncthreads();  // B2: x-tile dead, per-wave slices become live

  bf16_t* slice = &sX[w * 4096];
  // K -> wave slice [s][dd]
#pragma unroll
  for (int m = 0; m < 4; ++m)
#pragma unroll
    for (int n = 0; n < 4; ++n)
#pragma unroll
      for (int r = 0; r < 4; ++r)
        slice[ski(16 * m + 4 * g + r, 16 * n + l16)] = (bf16_t)ka[m][n][r];

  // ---- 3a: S^T = K @ Q^T (A = K from slice, B = Q^T from qtb via pair-shfl) ----
  f32x4 sc[4][4] = {};
#pragma unroll
  for (int ks = 0; ks < 2; ++ks) {
    const int ko = ks * 32 + 8 * g;
    bf16x8 ak[4];
#pragma unroll
    for (int m = 0; m < 4; ++m) ak[m] = *(const bf16x8*)&slice[ski(16 * m + l16, ko)];
    bf16x8 bq[4];
#pragma unroll
    for (int n = 0; n < 4; ++n) {
      union { u32 u[4]; bf16x8 v; } uu;
#pragma unroll
      for (int k2 = 0; k2 < 4; ++k2) {
        const int src = ((((2 * g + (k2 >> 1)) & 3) << 4) | l16);
        const u32 a0 = (u32)__shfl((int)qtb[2 * ks][n][k2 & 1], src);
        const u32 a1 = (u32)__shfl((int)qtb[2 * ks + 1][n][k2 & 1], src);
        uu.u[k2] = (g & 2) ? a1 : a0;
      }
      bq[n] = uu.v;
    }
#pragma unroll
    for (int m = 0; m < 4; ++m)
#pragma unroll
      for (int n = 0; n < 4; ++n) sc[m][n] = MFMA16(ak[m], bq[n], sc[m][n]);
  }

  // ---- 3b: causal softmax over s; P -> slice (overwrites K; all K reads done) ----
#pragma unroll
  for (int n = 0; n < 4; ++n) {
    const int t = 16 * n + l16;
    float vals[16];
    float mx = -3.0e38f;
#pragma unroll
    for (int m = 0; m < 4; ++m)
#pragma unroll
      for (int r = 0; r < 4; ++r) {
        const int s = 16 * m + 4 * g + r;
        const float v = (s <= t) ? sc[m][n][r] : -3.0e38f;
        vals[4 * m + r] = v;
        mx = fmaxf(mx, v);
      }
    mx = fmaxf(mx, __shfl_xor(mx, 16));
    mx = fmaxf(mx, __shfl_xor(mx, 32));
    float sum = 0.f;
#pragma unroll
    for (int i = 0; i < 16; ++i) {
      vals[i] = exp2f(vals[i] - mx);
      sum += vals[i];
    }
    sum += __shfl_xor(sum, 16);
    sum += __shfl_xor(sum, 32);
    const float inv = 1.0f / sum;
#pragma unroll
    for (int m = 0; m < 4; ++m) {
      bf16x4 p4;
#pragma unroll
      for (int r = 0; r < 4; ++r) p4[r] = (bf16_t)(vals[4 * m + r] * inv);
      *(bf16x4*)&slice[ski(t, 16 * m + 4 * g)] = p4;  // P[t][s..s+3]
    }
  }

  // ---- 3c: O = P @ V (A = P from slice; B = V from vb via pair-shfl) ----
  f32x4 oacc[4][4] = {};
#pragma unroll
  for (int ks = 0; ks < 2; ++ks) {
    const int ko = ks * 32 + 8 * g;
    bf16x8 ap[4];
#pragma unroll
    for (int m = 0; m < 4; ++m) ap[m] = *(const bf16x8*)&slice[ski(16 * m + l16, ko)];
    bf16x8 bv[4];
#pragma unroll
    for (int n = 0; n < 4; ++n) {
      union { u32 u[4]; bf16x8 v; } uu;
#pragma unroll
      for (int k2 = 0; k2 < 4; ++k2) {
        const int src = ((((2 * g + (k2 >> 1)) & 3) << 4) | l16);
        const u32 a0 = (u32)__shfl((int)vb[2 * ks][n][k2 & 1], src);
        const u32 a1 = (u32)__shfl((int)vb[2 * ks + 1][n][k2 & 1], src);
        uu.u[k2] = (g & 2) ? a1 : a0;
      }
      bv[n] = uu.v;
    }
#pragma unroll
    for (int m = 0; m < 4; ++m)
#pragma unroll
      for (int n = 0; n < 4; ++n) oacc[m][n] = MFMA16(ap[m], bv[n], oacc[m][n]);
  }
  __syncthreads();  // B3: all waves done with slices

  // ---- P4: O -> sX[t][w*64+d] ----
#pragma unroll
  for (int m = 0; m < 4; ++m)
#pragma unroll
    for (int n = 0; n < 4; ++n)
#pragma unroll
      for (int r = 0; r < 4; ++r)
        sX[sxi(16 * m + 4 * g + r, w * 64 + 16 * n + l16)] = (bf16_t)oacc[m][n][r];
  __syncthreads();  // B4

  // ---- P5: out = O @ w_out + b ----
  f32x4 acc[4][4] = {};
#pragma unroll
  for (int k0 = 0; k0 < 256; k0 += 32) {
    const int ko = k0 + 8 * g;
    bf16x8 af[4], bf[4];
#pragma unroll
    for (int m = 0; m < 4; ++m) af[m] = *(const bf16x8*)&sX[sxi(16 * m + l16, ko)];
#pragma unroll
    for (int n = 0; n < 4; ++n)
      bf[n] = *(const bf16x8*)&woutT[(size_t)(w * 64 + 16 * n + l16) * 256 + ko];
#pragma unroll
    for (int m = 0; m < 4; ++m)
#pragma unroll
      for (int n = 0; n < 4; ++n) acc[m][n] = MFMA16(af[m], bf[n], acc[m][n]);
  }
  float bb[4];
#pragma unroll
  for (int n = 0; n < 4; ++n) bb[n] = bout[w * 64 + 16 * n + l16];
#pragma unroll
  for (int m = 0; m < 4; ++m)
#pragma unroll
    for (int n = 0; n < 4; ++n)
#pragma unroll
      for (int r = 0; r < 4; ++r) {
        const int t = 16 * m + 4 * g + r;
        const int col = w * 64 + 16 * n + l16;
        op[(size_t)t * TS + col] = acc[m][n][r] + bb[n];
      }
}

// ---------------------------------------------------------------------------
extern "C" void kernel_launch(void* const* d_in, const int* in_sizes, int n_in,
                              void* d_out, int out_size, void* d_ws, size_t ws_size,
                              hipStream_t stream) {
  const float* x = (const float*)d_in[0];
  const float* wqkv = (const float*)d_in[1];
  const float* wout = (const float*)d_in[2];
  const float* bout = (const float*)d_in[3];
  const float* invf = (const float*)d_in[4];
  float* out = (float*)d_out;

  char* ws = (char*)d_ws;
  bf16_t* wqkvT = (bf16_t*)ws;                       // 768*256*2 = 393216 B
  bf16_t* woutT = (bf16_t*)(ws + 393216);            // 256*256*2 = 131072 B
  float2* ropecs = (float2*)(ws + 393216 + 131072);  // 2048*8 = 16384 B

  transpose_to_bf16<<<dim3(8, 24), dim3(32, 8), 0, stream>>>(wqkv, wqkvT, 256, 768);
  transpose_to_bf16<<<dim3(8, 8), dim3(32, 8), 0, stream>>>(wout, woutT, 256, 256);
  rope_table<<<8, 256, 0, stream>>>(invf, ropecs);

  taa_fused<<<2048, 256, 0, stream>>>(x, wqkvT, woutT, bout, ropecs, out);
}

// Round 7
// 282.711 us; speedup vs baseline: 2.6314x; 2.6314x over previous
//
#include <hip/hip_runtime.h>
#include <hip/hip_bf16.h>

typedef __bf16 bf16_t;
typedef bf16_t bf16x4 __attribute__((ext_vector_type(4)));
typedef bf16_t bf16x8 __attribute__((ext_vector_type(8)));
typedef float f32x4 __attribute__((ext_vector_type(4)));
typedef unsigned int u32;

#define MFMA16(a, b, c) __builtin_amdgcn_mfma_f32_16x16x32_bf16((a), (b), (c), 0, 0, 0)

// element-index XOR swizzles (bf16 elems): XOR bits 3..5 keyed by row&7
__device__ __forceinline__ int sxi(int row, int e) { return row * 256 + (e ^ ((row & 7) << 3)); }
__device__ __forceinline__ int ski(int row, int e) { return row * 64 + (e ^ ((row & 7) << 3)); }

__device__ __forceinline__ u32 pk2(float a, float b) {
  union { bf16_t h[2]; u32 u; } x;
  x.h[0] = (bf16_t)a; x.h[1] = (bf16_t)b;
  return x.u;
}

// ---------------------------------------------------------------------------
// prep kernels
// ---------------------------------------------------------------------------
__global__ void transpose_to_bf16(const float* __restrict__ in, bf16_t* __restrict__ outp,
                                  int K, int N) {
  __shared__ float tile[32][33];
  const int k0 = blockIdx.x * 32;
  const int n0 = blockIdx.y * 32;
  const int tx = threadIdx.x;
  const int ty = threadIdx.y;
#pragma unroll
  for (int i = 0; i < 32; i += 8)
    tile[ty + i][tx] = in[(size_t)(k0 + ty + i) * N + (n0 + tx)];
  __syncthreads();
#pragma unroll
  for (int i = 0; i < 32; i += 8)
    outp[(size_t)(n0 + ty + i) * K + (k0 + tx)] = (bf16_t)tile[tx][ty + i];
}

__global__ void rope_table(const float* __restrict__ invf, float2* __restrict__ cs) {
  const int idx = blockIdx.x * 256 + threadIdx.x;  // 0..2047 = 64*32
  const int t = idx >> 5;
  const int i = idx & 31;
  const float f = (float)t * invf[i];
  cs[idx] = make_float2(cosf(f), sinf(f));
}

// ---------------------------------------------------------------------------
// fused temporal-axial attention, 32KB LDS; x read from HBM exactly once.
// grid: 2048 = (b, hh*32+ww); block: 256 threads (4 waves, wave w = head w)
// No min-waves bound: avoids the arch-VGPR cap (256/minw) that spilled R5/R6.
// ---------------------------------------------------------------------------
__global__ __launch_bounds__(256) void taa_fused(
    const float* __restrict__ x, const bf16_t* __restrict__ wqkvT,
    const bf16_t* __restrict__ woutT, const float* __restrict__ bout,
    const float2* __restrict__ ropecs, float* __restrict__ out) {
  // x-tile[64][256] bf16 swizzled; after B2: 4 per-wave 8KB slices (K then P)
  __shared__ __attribute__((aligned(16))) bf16_t sX[64 * 256];  // 32 KB

  const int tid = threadIdx.x;
  const int w = tid >> 6;   // wave == head
  const int l = tid & 63;
  const int l16 = l & 15;
  const int g = l >> 4;  // 0..3

  const int site = blockIdx.x;
  const int b = site >> 10;
  const int sp = site & 1023;

  const size_t TS = 1024 * 256;  // time stride in elements
  const float* xp = x + (size_t)((b * 64) * 1024 + sp) * 256;
  float* op = out + (size_t)((b * 64) * 1024 + sp) * 256;

  // ---- P1: x tile (64x256 f32) -> sX bf16 (swizzled) ----
#pragma unroll
  for (int it = 0; it < 16; ++it) {
    const int idx = tid + it * 256;
    const int t = idx >> 6;
    const int c = (idx & 63) * 4;
    const float4 v = *(const float4*)(xp + (size_t)t * TS + c);
    bf16x4 o4;
    o4[0] = (bf16_t)v.x; o4[1] = (bf16_t)v.y; o4[2] = (bf16_t)v.z; o4[3] = (bf16_t)v.w;
    *(bf16x4*)&sX[sxi(t, c)] = o4;
  }
  __syncthreads();  // B1

  // ---- P2a: Q^T = WqT @ x^T  (C rows dd, cols t), rope, pack -> qtb (32 regs) ----
  u32 qtb[4][4][2];
  {
    f32x4 qt[4][4] = {};
#pragma unroll
    for (int k0 = 0; k0 < 256; k0 += 32) {
      const int ko = k0 + 8 * g;
      bf16x8 aw[4], bx[4];
#pragma unroll
      for (int m = 0; m < 4; ++m)
        aw[m] = *(const bf16x8*)&wqkvT[(size_t)(w * 64 + 16 * m + l16) * 256 + ko];
#pragma unroll
      for (int n = 0; n < 4; ++n) bx[n] = *(const bf16x8*)&sX[sxi(16 * n + l16, ko)];
#pragma unroll
      for (int m = 0; m < 4; ++m)
#pragma unroll
        for (int n = 0; n < 4; ++n) qt[m][n] = MFMA16(aw[m], bx[n], qt[m][n]);
    }
    // rope on Q^T: partner dd^1 lives in adjacent r of the same reg quad
    const float qs = 0.125f * 1.44269504088896f;
#pragma unroll
    for (int m = 0; m < 4; ++m)
#pragma unroll
      for (int n = 0; n < 4; ++n)
#pragma unroll
        for (int c = 0; c < 2; ++c) {
          const float v0 = qt[m][n][2 * c], v1 = qt[m][n][2 * c + 1];
          const float2 cs = ropecs[(16 * n + l16) * 32 + 8 * m + 2 * g + c];
          qtb[m][n][c] = pk2((v0 * cs.x - v1 * cs.y) * qs, (v1 * cs.x + v0 * cs.y) * qs);
        }
  }

  // ---- P2b: K = x @ Wk (C rows s, cols dd), rope, pack -> kb (32 regs) ----
  u32 kb[4][4][2];
  {
    f32x4 ka[4][4] = {};
#pragma unroll
    for (int k0 = 0; k0 < 256; k0 += 32) {
      const int ko = k0 + 8 * g;
      bf16x8 ax[4];
#pragma unroll
      for (int m = 0; m < 4; ++m) ax[m] = *(const bf16x8*)&sX[sxi(16 * m + l16, ko)];
#pragma unroll
      for (int n = 0; n < 4; ++n) {
        const bf16x8 bw = *(const bf16x8*)&wqkvT[(size_t)(256 + w * 64 + 16 * n + l16) * 256 + ko];
#pragma unroll
        for (int m = 0; m < 4; ++m) ka[m][n] = MFMA16(ax[m], bw, ka[m][n]);
      }
    }
    // rope K in place (partner lane l16^1), then pack pairs along r
#pragma unroll
    for (int m = 0; m < 4; ++m)
#pragma unroll
      for (int n = 0; n < 4; ++n) {
        f32x4 kr;
#pragma unroll
        for (int r = 0; r < 4; ++r) {
          const float v = ka[m][n][r];
          const float p = __shfl_xor(v, 1);
          const int s = 16 * m + 4 * g + r;
          const int dd = 16 * n + l16;
          const float2 cs = ropecs[s * 32 + 8 * n + (l16 >> 1)];
          kr[r] = (dd & 1) ? (v * cs.x + p * cs.y) : (v * cs.x - p * cs.y);
        }
#pragma unroll
        for (int c = 0; c < 2; ++c) kb[m][n][c] = pk2(kr[2 * c], kr[2 * c + 1]);
      }
  }

  // ---- P2c: V = x @ Wv (from LDS x-tile), pack -> vb (32 regs) ----
  u32 vb[4][4][2];
  {
    f32x4 va[4][4] = {};
#pragma unroll
    for (int k0 = 0; k0 < 256; k0 += 32) {
      const int ko = k0 + 8 * g;
      bf16x8 ax[4];
#pragma unroll
      for (int m = 0; m < 4; ++m) ax[m] = *(const bf16x8*)&sX[sxi(16 * m + l16, ko)];
#pragma unroll
      for (int n = 0; n < 4; ++n) {
        const bf16x8 bw = *(const bf16x8*)&wqkvT[(size_t)(512 + w * 64 + 16 * n + l16) * 256 + ko];
#pragma unroll
        for (int m = 0; m < 4; ++m) va[m][n] = MFMA16(ax[m], bw, va[m][n]);
      }
    }
#pragma unroll
    for (int m = 0; m < 4; ++m)
#pragma unroll
      for (int n = 0; n < 4; ++n)
#pragma unroll
        for (int c = 0; c < 2; ++c) vb[m][n][c] = pk2(va[m][n][2 * c], va[m][n][2 * c + 1]);
  }
  __syncthreads();  // B2: x-tile dead, per-wave slices become live

  bf16_t* slice = &sX[w * 4096];
  // unpack kb -> wave slice K[s][dd]
#pragma unroll
  for (int m = 0; m < 4; ++m)
#pragma unroll
    for (int n = 0; n < 4; ++n)
#pragma unroll
      for (int c = 0; c < 2; ++c) {
        union { u32 u; bf16_t h[2]; } uz;
        uz.u = kb[m][n][c];
        slice[ski(16 * m + 4 * g + 2 * c, 16 * n + l16)] = uz.h[0];
        slice[ski(16 * m + 4 * g + 2 * c + 1, 16 * n + l16)] = uz.h[1];
      }

  // ---- 3a: S^T = K @ Q^T (A = K from slice, B = Q^T from qtb via pair-shfl) ----
  f32x4 sc[4][4] = {};
#pragma unroll
  for (int ks = 0; ks < 2; ++ks) {
    const int ko = ks * 32 + 8 * g;
    bf16x8 ak[4];
#pragma unroll
    for (int m = 0; m < 4; ++m) ak[m] = *(const bf16x8*)&slice[ski(16 * m + l16, ko)];
#pragma unroll
    for (int n = 0; n < 4; ++n) {
      union { u32 u[4]; bf16x8 v; } uu;
#pragma unroll
      for (int k2 = 0; k2 < 4; ++k2) {
        const int src = ((((2 * g + (k2 >> 1)) & 3) << 4) | l16);
        const u32 a0 = (u32)__shfl((int)qtb[2 * ks][n][k2 & 1], src);
        const u32 a1 = (u32)__shfl((int)qtb[2 * ks + 1][n][k2 & 1], src);
        uu.u[k2] = (g & 2) ? a1 : a0;
      }
#pragma unroll
      for (int m = 0; m < 4; ++m) sc[m][n] = MFMA16(ak[m], uu.v, sc[m][n]);
    }
  }

  // ---- 3b: causal softmax over s; P -> slice (overwrites K; all K reads done) ----
#pragma unroll
  for (int n = 0; n < 4; ++n) {
    const int t = 16 * n + l16;
    float vals[16];
    float mx = -3.0e38f;
#pragma unroll
    for (int m = 0; m < 4; ++m)
#pragma unroll
      for (int r = 0; r < 4; ++r) {
        const int s = 16 * m + 4 * g + r;
        const float v = (s <= t) ? sc[m][n][r] : -3.0e38f;
        vals[4 * m + r] = v;
        mx = fmaxf(mx, v);
      }
    mx = fmaxf(mx, __shfl_xor(mx, 16));
    mx = fmaxf(mx, __shfl_xor(mx, 32));
    float sum = 0.f;
#pragma unroll
    for (int i = 0; i < 16; ++i) {
      vals[i] = exp2f(vals[i] - mx);
      sum += vals[i];
    }
    sum += __shfl_xor(sum, 16);
    sum += __shfl_xor(sum, 32);
    const float inv = 1.0f / sum;
#pragma unroll
    for (int m = 0; m < 4; ++m) {
      bf16x4 p4;
#pragma unroll
      for (int r = 0; r < 4; ++r) p4[r] = (bf16_t)(vals[4 * m + r] * inv);
      *(bf16x4*)&slice[ski(t, 16 * m + 4 * g)] = p4;  // P[t][s..s+3]
    }
  }

  // ---- 3c: O = P @ V (A = P from slice; B = V from vb via pair-shfl) ----
  f32x4 oacc[4][4] = {};
#pragma unroll
  for (int ks = 0; ks < 2; ++ks) {
    const int ko = ks * 32 + 8 * g;
    bf16x8 ap[4];
#pragma unroll
    for (int m = 0; m < 4; ++m) ap[m] = *(const bf16x8*)&slice[ski(16 * m + l16, ko)];
#pragma unroll
    for (int n = 0; n < 4; ++n) {
      union { u32 u[4]; bf16x8 v; } uu;
#pragma unroll
      for (int k2 = 0; k2 < 4; ++k2) {
        const int src = ((((2 * g + (k2 >> 1)) & 3) << 4) | l16);
        const u32 a0 = (u32)__shfl((int)vb[2 * ks][n][k2 & 1], src);
        const u32 a1 = (u32)__shfl((int)vb[2 * ks + 1][n][k2 & 1], src);
        uu.u[k2] = (g & 2) ? a1 : a0;
      }
#pragma unroll
      for (int m = 0; m < 4; ++m) oacc[m][n] = MFMA16(ap[m], uu.v, oacc[m][n]);
    }
  }
  __syncthreads();  // B3: all waves done with slices

  // ---- P4: O -> sX[t][w*64+d] ----
#pragma unroll
  for (int m = 0; m < 4; ++m)
#pragma unroll
    for (int n = 0; n < 4; ++n)
#pragma unroll
      for (int r = 0; r < 4; ++r)
        sX[sxi(16 * m + 4 * g + r, w * 64 + 16 * n + l16)] = (bf16_t)oacc[m][n][r];
  __syncthreads();  // B4

  // ---- P5: out = O @ w_out + b ----
  f32x4 acc[4][4] = {};
#pragma unroll
  for (int k0 = 0; k0 < 256; k0 += 32) {
    const int ko = k0 + 8 * g;
    bf16x8 af[4];
#pragma unroll
    for (int m = 0; m < 4; ++m) af[m] = *(const bf16x8*)&sX[sxi(16 * m + l16, ko)];
#pragma unroll
    for (int n = 0; n < 4; ++n) {
      const bf16x8 bw = *(const bf16x8*)&woutT[(size_t)(w * 64 + 16 * n + l16) * 256 + ko];
#pragma unroll
      for (int m = 0; m < 4; ++m) acc[m][n] = MFMA16(af[m], bw, acc[m][n]);
    }
  }
  float bb[4];
#pragma unroll
  for (int n = 0; n < 4; ++n) bb[n] = bout[w * 64 + 16 * n + l16];
#pragma unroll
  for (int m = 0; m < 4; ++m)
#pragma unroll
    for (int n = 0; n < 4; ++n)
#pragma unroll
      for (int r = 0; r < 4; ++r) {
        const int t = 16 * m + 4 * g + r;
        const int col = w * 64 + 16 * n + l16;
        op[(size_t)t * TS + col] = acc[m][n][r] + bb[n];
      }
}

// ---------------------------------------------------------------------------
extern "C" void kernel_launch(void* const* d_in, const int* in_sizes, int n_in,
                              void* d_out, int out_size, void* d_ws, size_t ws_size,
                              hipStream_t stream) {
  const float* x = (const float*)d_in[0];
  const float* wqkv = (const float*)d_in[1];
  const float* wout = (const float*)d_in[2];
  const float* bout = (const float*)d_in[3];
  const float* invf = (const float*)d_in[4];
  float* out = (float*)d_out;

  char* ws = (char*)d_ws;
  bf16_t* wqkvT = (bf16_t*)ws;                       // 768*256*2 = 393216 B
  bf16_t* woutT = (bf16_t*)(ws + 393216);            // 256*256*2 = 131072 B
  float2* ropecs = (float2*)(ws + 393216 + 131072);  // 2048*8 = 16384 B

  transpose_to_bf16<<<dim3(8, 24), dim3(32, 8), 0, stream>>>(wqkv, wqkvT, 256, 768);
  transpose_to_bf16<<<dim3(8, 8), dim3(32, 8), 0, stream>>>(wout, woutT, 256, 256);
  rope_table<<<8, 256, 0, stream>>>(invf, ropecs);

  taa_fused<<<2048, 256, 0, stream>>>(x, wqkvT, woutT, bout, ropecs, out);
}